// Round 7
// baseline (714.045 us; speedup 1.0000x reference)
//
#include <hip/hip_runtime.h>
#include <hip/hip_bf16.h>
#include <stdint.h>

#define NN 10000
#define NE 160000
#define INF 256
#define CH 512
#define NL 1440
#define MPAN 158   // ceil(10000/64) A panels (64-row)

typedef __bf16 bf16;
typedef __attribute__((ext_vector_type(8))) bf16 bf16x8;
typedef __attribute__((ext_vector_type(4))) bf16 bf16x4;
typedef __attribute__((ext_vector_type(4))) float f32x4;

// A tiled layout: [panel(64 rows)][chunk(32 k')][g=4][row=64][j=8]   (2048 elem/chunk/plane)
// B tiled layout: [panel(128 cols)][chunk(32 k')][g=4][col=128][j=8] (4096 elem/chunk/plane)
// hi-plane chunks 0..KCh-1, lo-plane chunks KCh..2KCh-1. Unit order == stager lane order.
// GEMM is 2-pass split: C = ah*bh + al*bh  (A exact, B effectively bf16).

__device__ __forceinline__ void gload16(const void* g, const void* l) {
    auto gp = reinterpret_cast<const __attribute__((address_space(1))) uint32_t*>(
        reinterpret_cast<uintptr_t>(g));
    auto lp = reinterpret_cast<__attribute__((address_space(3))) uint32_t*>(
        reinterpret_cast<uintptr_t>(l));
    __builtin_amdgcn_global_load_lds(gp, lp, 16, 0, 0);
}

// ---------------- graph prep ----------------
__global__ void deg_kernel(const int* __restrict__ src, const int* __restrict__ dst,
                           int* __restrict__ deg_out, int* __restrict__ deg_in) {
    int e = blockIdx.x * 256 + threadIdx.x;
    if (e < NE) {
        atomicAdd(&deg_out[src[e]], 1);
        atomicAdd(&deg_in[dst[e]], 1);
    }
}

__global__ __launch_bounds__(1024) void scan_kernel(const int* __restrict__ deg,
                                                    int* __restrict__ offsets,
                                                    int* __restrict__ cursor) {
    __shared__ int sums[1024];
    const int PER = 10;
    int tid = threadIdx.x;
    int base = tid * PER;
    int local[PER];
    int s = 0;
    #pragma unroll
    for (int i = 0; i < PER; i++) {
        int v = (base + i < NN) ? deg[base + i] : 0;
        local[i] = s;
        s += v;
    }
    sums[tid] = s;
    __syncthreads();
    for (int off = 1; off < 1024; off <<= 1) {
        int v = (tid >= off) ? sums[tid - off] : 0;
        __syncthreads();
        sums[tid] += v;
        __syncthreads();
    }
    int prev = (tid > 0) ? sums[tid - 1] : 0;
    #pragma unroll
    for (int i = 0; i < PER; i++) {
        if (base + i < NN) {
            int o = prev + local[i];
            offsets[base + i] = o;
            cursor[base + i] = o;
        }
    }
    if (tid == 0) offsets[NN] = sums[1023];
}

__global__ void csr_kernel(const int* __restrict__ src, const int* __restrict__ dst,
                           const int* __restrict__ deg_out, const int* __restrict__ deg_in,
                           int* __restrict__ cursor, int* __restrict__ edge_dst,
                           float* __restrict__ edge_w) {
    int e = blockIdx.x * 256 + threadIdx.x;
    if (e < NE) {
        int s = src[e], d = dst[e];
        float dw = (float)max(deg_out[s], 1) * (float)max(deg_in[d], 1);
        float w = rsqrtf(dw);
        int pos = atomicAdd(&cursor[s], 1);
        edge_dst[pos] = d;
        edge_w[pos] = w;
    }
}

// ------- XCD-sliced aggregate + residual + relu + split-to-tiled -------
// grid = 8 slices x ceil(NN/4); slice = blockIdx&7 -> pinned to one XCD by
// round-robin dispatch, so each XCD's gather working set is mb[:,slice] = 1.25 MB
// (L2-resident). One wave per node; lane = channel within slice.
__global__ __launch_bounds__(256) void agg_fuse(
    const bf16* __restrict__ mb,     // [NN][512] bf16
    const float* __restrict__ pb,    // [NN][512] f32
    const float* __restrict__ bias,  // [512]
    const int* __restrict__ offsets,
    const int* __restrict__ edge_dst,
    const float* __restrict__ edge_w,
    bf16* __restrict__ outT) {       // A-tiled split, 32 chunks (hi 0..15 | lo 16..31)
    int p = blockIdx.x;
    int slice = p & 7;
    int grp = p >> 3;
    int wid = threadIdx.x >> 6;
    int lane = threadIdx.x & 63;
    int u = grp * 4 + wid;
    if (u >= NN) return;
    int c = slice * 64 + lane;

    int beg = offsets[u], end = offsets[u + 1];
    float a = 0.f;
    int e = beg;
    for (; e + 1 < end; e += 2) {
        int d0 = edge_dst[e], d1 = edge_dst[e + 1];
        float w0 = edge_w[e], w1 = edge_w[e + 1];
        float m0 = (float)mb[d0 * 512 + c];
        float m1 = (float)mb[d1 * 512 + c];
        a += w0 * m0;
        a += w1 * m1;
    }
    if (e < end) a += edge_w[e] * (float)mb[edge_dst[e] * 512 + c];

    float v = fmaxf(a + pb[(size_t)u * 512 + c] + bias[c], 0.f);
    bf16 h = (bf16)v;
    bf16 l = (bf16)(v - (float)h);

    int row = u & 63, panel = u >> 6;
    int ch = c >> 5, g = (c >> 3) & 3, j = c & 7;
    size_t base = (size_t)panel * 32 * 2048 + (size_t)ch * 2048 + g * 512 + row * 8 + j;
    outT[base] = h;
    outT[base + 16 * 2048] = l;
}

// ---------------- f32 [M][K] -> tiled split bf16 (A layout, 64-row panels) ------------
__global__ void split_rows(const float* __restrict__ in, bf16* __restrict__ out,
                           int M, int K) {
    int idx = blockIdx.x * 256 + threadIdx.x;
    int K4 = K >> 2;
    if (idx >= M * K4) return;
    int m = idx / K4;
    int k4 = (idx % K4) * 4;
    int KCh = K >> 5;
    int KC2 = KCh * 2;
    float4 v = *(const float4*)&in[(size_t)m * K + k4];
    float vv[4] = {v.x, v.y, v.z, v.w};
    bf16x4 hi, lo;
    #pragma unroll
    for (int j = 0; j < 4; j++) {
        bf16 h = (bf16)vv[j];
        hi[j] = h;
        lo[j] = (bf16)(vv[j] - (float)h);
    }
    int panel = m >> 6, row = m & 63;
    int c = k4 >> 5, g = (k4 & 31) >> 3, j0 = k4 & 7;
    size_t base = ((size_t)panel * KC2) * 2048 + g * 512 + row * 8 + j0;
    *(bf16x4*)&out[base + (size_t)c * 2048] = hi;
    *(bf16x4*)&out[base + (size_t)(KCh + c) * 2048] = lo;
}

// ---------------- W[K][N] f32 -> tiled bf16-hi (B^T layout, 128-col panels) -----------
__global__ void tsplit(const float* __restrict__ in, bf16* __restrict__ out,
                       int K, int N, size_t inStride, size_t outStride) {
    int z = blockIdx.z;
    in += (size_t)z * inStride;
    out += (size_t)z * outStride;
    int idx = blockIdx.x * 256 + threadIdx.x;
    int K8 = K >> 3;
    if (idx >= N * K8) return;
    int k8 = (idx / N) * 8;
    int n = idx % N;
    int KCh = K >> 5;
    bf16x8 hi;
    #pragma unroll
    for (int j = 0; j < 8; j++) hi[j] = (bf16)in[(size_t)(k8 + j) * N + n];
    int panel = n >> 7, row = n & 127;
    int c = k8 >> 5, g = (k8 & 31) >> 3;
    size_t base = ((size_t)panel * KCh) * 4096 + g * 1024 + row * 8;
    *(bf16x8*)&out[base + (size_t)c * 4096] = hi;
}

// ---------------- shared GEMM core (128x128 tile, 2-pass split) ----------------
#define GEMM_PROLOGUE()                                                           \
    int nwg = gridDim.x;                                                          \
    int q = nwg >> 3, r = nwg & 7;                                                \
    int p = blockIdx.x;                                                           \
    int xcd = p & 7, slot = p >> 3;                                               \
    int L = (xcd < r ? xcd * (q + 1) : r * (q + 1) + (xcd - r) * q) + slot;       \
    int by = L / BX, bx = L % BX;                                                 \
    int tid = threadIdx.x;                                                        \
    int lane = tid & 63, w = tid >> 6;                                            \
    int wm = w >> 1, wn = w & 1;                                                  \
    int lr = lane & 15, lg = lane >> 4;                                           \
    const bf16* Ab0 = At + (size_t)(2 * by) * (KCh * 2) * 2048;                   \
    const bf16* Ab1 = At + (size_t)(2 * by + 1) * (KCh * 2) * 2048;               \
    const bf16* Bbase = Bt + (size_t)bx * KCh * 4096;                             \
    f32x4 acc[4][4];                                                              \
    _Pragma("unroll") for (int i = 0; i < 4; i++)                                 \
        _Pragma("unroll") for (int j = 0; j < 4; j++) {                           \
            f32x4 z = {0.f, 0.f, 0.f, 0.f};                                       \
            acc[i][j] = z;                                                        \
        }                                                                         \
    int u0 = tid, u1 = tid + 256;                                                 \
    int offA = lg * 512 + lr * 8;                                                 \
    int offB = lg * 1024 + (wn * 64 + lr) * 8;

#define STAGE(bufi, t)                                                            \
    do {                                                                          \
        const bf16* s0h = Ab0 + (size_t)(t) * 2048;                               \
        const bf16* s1h = Ab1 + (size_t)(t) * 2048;                               \
        const bf16* s0l = Ab0 + (size_t)(KCh + (t)) * 2048;                       \
        const bf16* s1l = Ab1 + (size_t)(KCh + (t)) * 2048;                       \
        const bf16* sBh = Bbase + (size_t)(t) * 4096;                             \
        gload16(s0h + tid * 8, &ldsA[bufi][0][0][tid * 8]);                       \
        gload16(s1h + tid * 8, &ldsA[bufi][0][1][tid * 8]);                       \
        gload16(s0l + tid * 8, &ldsA[bufi][1][0][tid * 8]);                       \
        gload16(s1l + tid * 8, &ldsA[bufi][1][1][tid * 8]);                       \
        gload16(sBh + u0 * 8, &ldsB[bufi][u0 * 8]);                               \
        gload16(sBh + u1 * 8, &ldsB[bufi][u1 * 8]);                               \
    } while (0)

#define GEMM_MAINLOOP()                                                           \
    STAGE(0, 0);                                                                  \
    __syncthreads();                                                              \
    int buf = 0;                                                                  \
    for (int t = 0; t < KCh; t++) {                                               \
        if (t + 1 < KCh) STAGE(buf ^ 1, t + 1);                                   \
        bf16x8 bh[4];                                                             \
        _Pragma("unroll") for (int n = 0; n < 4; n++)                             \
            bh[n] = *(const bf16x8*)&ldsB[buf][offB + n * 128];                   \
        _Pragma("unroll") for (int m = 0; m < 4; m++) {                           \
            bf16x8 ah = *(const bf16x8*)&ldsA[buf][0][wm][offA + m * 128];        \
            bf16x8 al = *(const bf16x8*)&ldsA[buf][1][wm][offA + m * 128];        \
            _Pragma("unroll") for (int n = 0; n < 4; n++) {                       \
                acc[m][n] = __builtin_amdgcn_mfma_f32_16x16x32_bf16(              \
                    ah, bh[n], acc[m][n], 0, 0, 0);                               \
                acc[m][n] = __builtin_amdgcn_mfma_f32_16x16x32_bf16(              \
                    al, bh[n], acc[m][n], 0, 0, 0);                               \
            }                                                                     \
        }                                                                         \
        __syncthreads();                                                          \
        buf ^= 1;                                                                 \
    }

// ---------------- WV-GEMM: A @ [W|V] -> m (bf16, cols 0..511) + p (f32, 512..1023) ----
__global__ __launch_bounds__(256, 3) void gemm_wv(
    const bf16* __restrict__ At, const bf16* __restrict__ Bt,
    bf16* __restrict__ mOut, float* __restrict__ pOut,
    int M, int KCh, int BX) {
    __shared__ bf16 ldsA[2][2][2][2048];  // [buf][plane][panel-half][64r x 32k]
    __shared__ bf16 ldsB[2][4096];        // [buf][128c x 32k] hi only
    GEMM_PROLOGUE();
    GEMM_MAINLOOP();

    int m0 = by * 128, n0 = bx * 128;
    if (n0 < 512) {  // m plane: bf16
        #pragma unroll
        for (int m = 0; m < 4; m++)
            #pragma unroll
            for (int n = 0; n < 4; n++) {
                int grow0 = m0 + wm * 64 + m * 16 + lg * 4;
                int gcol = n0 + wn * 64 + n * 16 + lr;
                #pragma unroll
                for (int r2 = 0; r2 < 4; r2++) {
                    int grow = grow0 + r2;
                    if (grow < M) mOut[(size_t)grow * 512 + gcol] = (bf16)acc[m][n][r2];
                }
            }
    } else {  // p plane: f32
        #pragma unroll
        for (int m = 0; m < 4; m++)
            #pragma unroll
            for (int n = 0; n < 4; n++) {
                int grow0 = m0 + wm * 64 + m * 16 + lg * 4;
                int gcol = n0 - 512 + wn * 64 + n * 16 + lr;
                #pragma unroll
                for (int r2 = 0; r2 < 4; r2++) {
                    int grow = grow0 + r2;
                    if (grow < M) pOut[(size_t)grow * 512 + gcol] = acc[m][n][r2];
                }
            }
    }
}

// ---------------- final GEMM: A @ Wd + bd -> f32 out ----------------
__global__ __launch_bounds__(256, 3) void gemm_out(
    const bf16* __restrict__ At, const bf16* __restrict__ Bt,
    float* __restrict__ Fout, const float* __restrict__ bias,
    int M, int N, int KCh, int BX) {
    __shared__ bf16 ldsA[2][2][2][2048];
    __shared__ bf16 ldsB[2][4096];
    GEMM_PROLOGUE();
    GEMM_MAINLOOP();

    int m0 = by * 128, n0 = bx * 128;
    #pragma unroll
    for (int m = 0; m < 4; m++)
        #pragma unroll
        for (int n = 0; n < 4; n++) {
            int grow0 = m0 + wm * 64 + m * 16 + lg * 4;
            int gcol = n0 + wn * 64 + n * 16 + lr;
            if (gcol >= N) continue;
            float bv = bias[gcol];
            #pragma unroll
            for (int r2 = 0; r2 < 4; r2++) {
                int grow = grow0 + r2;
                if (grow < M) Fout[(size_t)grow * N + gcol] = acc[m][n][r2] + bv;
            }
        }
}

// ---------------- host launch ----------------
extern "C" void kernel_launch(void* const* d_in, const int* in_sizes, int n_in,
                              void* d_out, int out_size, void* d_ws, size_t ws_size,
                              hipStream_t stream) {
    const float* x  = (const float*)d_in[0];
    const int* src  = (const int*)d_in[1];
    const int* dst  = (const int*)d_in[2];
    const float* W1 = (const float*)d_in[3];
    const float* V1 = (const float*)d_in[4];
    const float* b1 = (const float*)d_in[5];
    const float* Wk = (const float*)d_in[6];
    const float* Vk = (const float*)d_in[7];
    const float* bk = (const float*)d_in[8];
    const float* Wd = (const float*)d_in[9];
    const float* bd = (const float*)d_in[10];

    // ws layout
    int* deg_out  = (int*)d_ws;
    int* deg_in   = deg_out + 10240;
    int* offsets  = deg_in + 10240;
    int* cursor   = offsets + 10240;
    int* edge_dst = cursor + 10240;
    float* edge_w = (float*)(edge_dst + NE);
    bf16* bufA    = (bf16*)(edge_w + NE);               // MPAN x 32 x 2048
    bf16* bufB    = bufA + (size_t)MPAN * 32 * 2048;
    bf16* w1v1t   = bufB + (size_t)MPAN * 32 * 2048;    // 8 panels x 8 x 4096 (hi only)
    bf16* wvkt    = w1v1t + (size_t)8 * 8 * 4096;       // 6 x 8 panels x 16 x 4096
    bf16* wdt     = wvkt + (size_t)6 * 8 * 16 * 4096;   // 12 panels x 16 x 4096

    // d_out doubles as m/p scratch (dead before final GEMM writes)
    float* pb = (float*)d_out;                          // [NN][512] f32
    bf16* mb  = (bf16*)(pb + (size_t)NN * 512);         // [NN][512] bf16
    float* out = (float*)d_out;

    hipMemsetAsync(deg_out, 0, 2 * 10240 * sizeof(int), stream);
    deg_kernel<<<(NE + 255) / 256, 256, 0, stream>>>(src, dst, deg_out, deg_in);
    scan_kernel<<<1, 1024, 0, stream>>>(deg_out, offsets, cursor);
    csr_kernel<<<(NE + 255) / 256, 256, 0, stream>>>(src, dst, deg_out, deg_in,
                                                     cursor, edge_dst, edge_w);

    // one-time conversions (B side stores hi plane only)
    split_rows<<<(NN * (INF / 4) + 255) / 256, 256, 0, stream>>>(x, bufA, NN, INF);
    tsplit<<<dim3((512 * (INF / 8) + 255) / 256, 1, 1), 256, 0, stream>>>(
        W1, w1v1t, INF, 512, 0, 0);
    tsplit<<<dim3((512 * (INF / 8) + 255) / 256, 1, 1), 256, 0, stream>>>(
        V1, w1v1t + (size_t)4 * 8 * 4096, INF, 512, 0, 0);
    tsplit<<<dim3((512 * (CH / 8) + 255) / 256, 1, 6), 256, 0, stream>>>(
        Wk, wvkt, CH, 512, (size_t)CH * 512, (size_t)8 * 16 * 4096);
    tsplit<<<dim3((512 * (CH / 8) + 255) / 256, 1, 6), 256, 0, stream>>>(
        Vk, wvkt + (size_t)4 * 16 * 4096, CH, 512, (size_t)CH * 512,
        (size_t)8 * 16 * 4096);
    tsplit<<<dim3((NL * (CH / 8) + 255) / 256, 1, 1), 256, 0, stream>>>(
        Wd, wdt, CH, NL, 0, 0);

    dim3 blk(256);
    int gwv = (MPAN / 2) * 8;     // 632 blocks (128-row tiles x 8 col-tiles)
    int gout = (MPAN / 2) * 12;   // 948 blocks
    int gagg = 8 * ((NN + 3) / 4);  // 8 XCD slices x node groups of 4

    // layer 1 (K = 256, KCh = 8)
    gemm_wv<<<gwv, blk, 0, stream>>>(bufA, w1v1t, mb, pb, NN, 8, 8);
    agg_fuse<<<gagg, blk, 0, stream>>>(mb, pb, b1, offsets, edge_dst, edge_w, bufB);

    bf16* cur = bufB;
    bf16* nxt = bufA;
    for (int i = 0; i < 6; i++) {
        const bf16* WV = wvkt + (size_t)i * 8 * 16 * 4096;
        gemm_wv<<<gwv, blk, 0, stream>>>(cur, WV, mb, pb, NN, 16, 8);
        agg_fuse<<<gagg, blk, 0, stream>>>(mb, pb, bk + (size_t)i * CH, offsets,
                                           edge_dst, edge_w, nxt);
        bf16* t = cur; cur = nxt; nxt = t;
    }

    // output: out = h @ Wd + bd  (K = 512, N = 1440)
    gemm_out<<<gout, blk, 0, stream>>>(cur, wdt, out, bd, NN, NL, 16, 12);
}

// Round 8
// 512.816 us; speedup vs baseline: 1.3924x; 1.3924x over previous
//
#include <hip/hip_runtime.h>
#include <hip/hip_bf16.h>
#include <stdint.h>

#define NN 10000
#define NE 160000
#define INF 256
#define CH 512
#define NL 1440
#define MPAN 158   // ceil(10000/64) A panels (64-row)

typedef __bf16 bf16;
typedef __attribute__((ext_vector_type(8))) bf16 bf16x8;
typedef __attribute__((ext_vector_type(4))) bf16 bf16x4;
typedef __attribute__((ext_vector_type(4))) float f32x4;

// A tiled layout: [panel(64 rows)][chunk(32 k')][g=4][row=64][j=8]   (2048 elem/chunk/plane)
// B tiled layout: [panel(128 cols)][chunk(32 k')][g=4][col=128][j=8] (4096 elem/chunk/plane)
// hi-plane chunks 0..KCh-1, lo-plane chunks KCh..2KCh-1. Unit order == stager lane order.
// GEMM is 2-pass split: C = ah*bh + al*bh  (A exact, B effectively bf16).

__device__ __forceinline__ void gload16(const void* g, const void* l) {
    auto gp = reinterpret_cast<const __attribute__((address_space(1))) uint32_t*>(
        reinterpret_cast<uintptr_t>(g));
    auto lp = reinterpret_cast<__attribute__((address_space(3))) uint32_t*>(
        reinterpret_cast<uintptr_t>(l));
    __builtin_amdgcn_global_load_lds(gp, lp, 16, 0, 0);
}

// ---------------- graph prep ----------------
__global__ void deg_kernel(const int* __restrict__ src, const int* __restrict__ dst,
                           int* __restrict__ deg_out, int* __restrict__ deg_in) {
    int e = blockIdx.x * 256 + threadIdx.x;
    if (e < NE) {
        atomicAdd(&deg_out[src[e]], 1);
        atomicAdd(&deg_in[dst[e]], 1);
    }
}

__global__ __launch_bounds__(1024) void scan_kernel(const int* __restrict__ deg,
                                                    int* __restrict__ offsets,
                                                    int* __restrict__ cursor) {
    __shared__ int sums[1024];
    const int PER = 10;
    int tid = threadIdx.x;
    int base = tid * PER;
    int local[PER];
    int s = 0;
    #pragma unroll
    for (int i = 0; i < PER; i++) {
        int v = (base + i < NN) ? deg[base + i] : 0;
        local[i] = s;
        s += v;
    }
    sums[tid] = s;
    __syncthreads();
    for (int off = 1; off < 1024; off <<= 1) {
        int v = (tid >= off) ? sums[tid - off] : 0;
        __syncthreads();
        sums[tid] += v;
        __syncthreads();
    }
    int prev = (tid > 0) ? sums[tid - 1] : 0;
    #pragma unroll
    for (int i = 0; i < PER; i++) {
        if (base + i < NN) {
            int o = prev + local[i];
            offsets[base + i] = o;
            cursor[base + i] = o;
        }
    }
    if (tid == 0) offsets[NN] = sums[1023];
}

__global__ void csr_kernel(const int* __restrict__ src, const int* __restrict__ dst,
                           const int* __restrict__ deg_out, const int* __restrict__ deg_in,
                           int* __restrict__ cursor, int2* __restrict__ edge_pk) {
    int e = blockIdx.x * 256 + threadIdx.x;
    if (e < NE) {
        int s = src[e], d = dst[e];
        float dw = (float)max(deg_out[s], 1) * (float)max(deg_in[d], 1);
        float w = rsqrtf(dw);
        int pos = atomicAdd(&cursor[s], 1);
        edge_pk[pos] = make_int2(d, __float_as_int(w));
    }
}

// ------- XCD-sliced aggregate + residual + relu + split-to-tiled -------
// 4 slices x 128 channels; slice = blockIdx&3 -> pinned to XCDs {s, s+4} by
// round-robin dispatch; per-XCD mb slice = 2.56 MB (L2-resident).
// One wave per node per slice; lane handles 2 consecutive channels via u32 gather.
__global__ __launch_bounds__(256) void agg_fuse(
    const bf16* __restrict__ mb,     // [NN][512] bf16
    const float* __restrict__ pb,    // [NN][512] f32
    const float* __restrict__ bias,  // [512]
    const int* __restrict__ offsets,
    const int2* __restrict__ edge_pk,
    bf16* __restrict__ outT) {       // A-tiled split, 32 chunks (hi 0..15 | lo 16..31)
    int p = blockIdx.x;
    int slice = p & 3;
    int grp = p >> 2;
    int wid = threadIdx.x >> 6;
    int lane = threadIdx.x & 63;
    int u = grp * 4 + wid;
    if (u >= NN) return;
    int c = slice * 128 + lane * 2;          // 2 consecutive channels
    int cu = slice * 64 + lane;              // u32 index within 256-u32 row
    const uint32_t* mb32 = (const uint32_t*)mb;

    int beg = offsets[u], end = offsets[u + 1];
    float a0 = 0.f, a1 = 0.f;
    int e = beg;
    for (; e + 3 < end; e += 4) {
        int2 p0 = edge_pk[e], p1 = edge_pk[e + 1];
        int2 p2 = edge_pk[e + 2], p3 = edge_pk[e + 3];
        uint32_t q0 = mb32[p0.x * 256 + cu];
        uint32_t q1 = mb32[p1.x * 256 + cu];
        uint32_t q2 = mb32[p2.x * 256 + cu];
        uint32_t q3 = mb32[p3.x * 256 + cu];
        float w0 = __int_as_float(p0.y), w1 = __int_as_float(p1.y);
        float w2 = __int_as_float(p2.y), w3 = __int_as_float(p3.y);
        a0 += w0 * __uint_as_float(q0 << 16);
        a1 += w0 * __uint_as_float(q0 & 0xffff0000u);
        a0 += w1 * __uint_as_float(q1 << 16);
        a1 += w1 * __uint_as_float(q1 & 0xffff0000u);
        a0 += w2 * __uint_as_float(q2 << 16);
        a1 += w2 * __uint_as_float(q2 & 0xffff0000u);
        a0 += w3 * __uint_as_float(q3 << 16);
        a1 += w3 * __uint_as_float(q3 & 0xffff0000u);
    }
    for (; e < end; e++) {
        int2 pe = edge_pk[e];
        uint32_t q = mb32[pe.x * 256 + cu];
        float wt = __int_as_float(pe.y);
        a0 += wt * __uint_as_float(q << 16);
        a1 += wt * __uint_as_float(q & 0xffff0000u);
    }

    float2 pv = *(const float2*)&pb[(size_t)u * 512 + c];
    float2 bv = *(const float2*)&bias[c];
    float v0 = fmaxf(a0 + pv.x + bv.x, 0.f);
    float v1 = fmaxf(a1 + pv.y + bv.y, 0.f);
    bf16 h0 = (bf16)v0, h1 = (bf16)v1;
    bf16 l0 = (bf16)(v0 - (float)h0), l1 = (bf16)(v1 - (float)h1);

    int row = u & 63, panel = u >> 6;
    int ch = c >> 5, g = (c >> 3) & 3, j = c & 7;   // j even
    size_t base = (size_t)panel * 32 * 2048 + (size_t)ch * 2048 + g * 512 + row * 8 + j;
    uint32_t hw = (uint32_t)__builtin_bit_cast(uint16_t, h0) |
                  ((uint32_t)__builtin_bit_cast(uint16_t, h1) << 16);
    uint32_t lw = (uint32_t)__builtin_bit_cast(uint16_t, l0) |
                  ((uint32_t)__builtin_bit_cast(uint16_t, l1) << 16);
    *(uint32_t*)&outT[base] = hw;
    *(uint32_t*)&outT[base + 16 * 2048] = lw;
}

// ---------------- f32 [M][K] -> tiled split bf16 (A layout, 64-row panels) ------------
__global__ void split_rows(const float* __restrict__ in, bf16* __restrict__ out,
                           int M, int K) {
    int idx = blockIdx.x * 256 + threadIdx.x;
    int K4 = K >> 2;
    if (idx >= M * K4) return;
    int m = idx / K4;
    int k4 = (idx % K4) * 4;
    int KCh = K >> 5;
    int KC2 = KCh * 2;
    float4 v = *(const float4*)&in[(size_t)m * K + k4];
    float vv[4] = {v.x, v.y, v.z, v.w};
    bf16x4 hi, lo;
    #pragma unroll
    for (int j = 0; j < 4; j++) {
        bf16 h = (bf16)vv[j];
        hi[j] = h;
        lo[j] = (bf16)(vv[j] - (float)h);
    }
    int panel = m >> 6, row = m & 63;
    int c = k4 >> 5, g = (k4 & 31) >> 3, j0 = k4 & 7;
    size_t base = ((size_t)panel * KC2) * 2048 + g * 512 + row * 8 + j0;
    *(bf16x4*)&out[base + (size_t)c * 2048] = hi;
    *(bf16x4*)&out[base + (size_t)(KCh + c) * 2048] = lo;
}

// ---------------- W[K][N] f32 -> tiled bf16-hi (B^T layout, 128-col panels) -----------
__global__ void tsplit(const float* __restrict__ in, bf16* __restrict__ out,
                       int K, int N, size_t inStride, size_t outStride) {
    int z = blockIdx.z;
    in += (size_t)z * inStride;
    out += (size_t)z * outStride;
    int idx = blockIdx.x * 256 + threadIdx.x;
    int K8 = K >> 3;
    if (idx >= N * K8) return;
    int k8 = (idx / N) * 8;
    int n = idx % N;
    int KCh = K >> 5;
    bf16x8 hi;
    #pragma unroll
    for (int j = 0; j < 8; j++) hi[j] = (bf16)in[(size_t)(k8 + j) * N + n];
    int panel = n >> 7, row = n & 127;
    int c = k8 >> 5, g = (k8 & 31) >> 3;
    size_t base = ((size_t)panel * KCh) * 4096 + g * 1024 + row * 8;
    *(bf16x8*)&out[base + (size_t)c * 4096] = hi;
}

// ---------------- shared GEMM core (128x128 tile, 2-pass split) ----------------
#define GEMM_PROLOGUE()                                                           \
    int nwg = gridDim.x;                                                          \
    int q = nwg >> 3, r = nwg & 7;                                                \
    int p = blockIdx.x;                                                           \
    int xcd = p & 7, slot = p >> 3;                                               \
    int L = (xcd < r ? xcd * (q + 1) : r * (q + 1) + (xcd - r) * q) + slot;       \
    int by = L / BX, bx = L % BX;                                                 \
    int tid = threadIdx.x;                                                        \
    int lane = tid & 63, w = tid >> 6;                                            \
    int wm = w >> 1, wn = w & 1;                                                  \
    int lr = lane & 15, lg = lane >> 4;                                           \
    const bf16* Ab0 = At + (size_t)(2 * by) * (KCh * 2) * 2048;                   \
    const bf16* Ab1 = At + (size_t)(2 * by + 1) * (KCh * 2) * 2048;               \
    const bf16* Bbase = Bt + (size_t)bx * KCh * 4096;                             \
    f32x4 acc[4][4];                                                              \
    _Pragma("unroll") for (int i = 0; i < 4; i++)                                 \
        _Pragma("unroll") for (int j = 0; j < 4; j++) {                           \
            f32x4 z = {0.f, 0.f, 0.f, 0.f};                                       \
            acc[i][j] = z;                                                        \
        }                                                                         \
    int u0 = tid, u1 = tid + 256;                                                 \
    int offA = lg * 512 + lr * 8;                                                 \
    int offB = lg * 1024 + (wn * 64 + lr) * 8;

#define STAGE(bufi, t)                                                            \
    do {                                                                          \
        const bf16* s0h = Ab0 + (size_t)(t) * 2048;                               \
        const bf16* s1h = Ab1 + (size_t)(t) * 2048;                               \
        const bf16* s0l = Ab0 + (size_t)(KCh + (t)) * 2048;                       \
        const bf16* s1l = Ab1 + (size_t)(KCh + (t)) * 2048;                       \
        const bf16* sBh = Bbase + (size_t)(t) * 4096;                             \
        gload16(s0h + tid * 8, &ldsA[bufi][0][0][tid * 8]);                       \
        gload16(s1h + tid * 8, &ldsA[bufi][0][1][tid * 8]);                       \
        gload16(s0l + tid * 8, &ldsA[bufi][1][0][tid * 8]);                       \
        gload16(s1l + tid * 8, &ldsA[bufi][1][1][tid * 8]);                       \
        gload16(sBh + u0 * 8, &ldsB[bufi][u0 * 8]);                               \
        gload16(sBh + u1 * 8, &ldsB[bufi][u1 * 8]);                               \
    } while (0)

#define GEMM_MAINLOOP()                                                           \
    STAGE(0, 0);                                                                  \
    __syncthreads();                                                              \
    int buf = 0;                                                                  \
    for (int t = 0; t < KCh; t++) {                                               \
        if (t + 1 < KCh) STAGE(buf ^ 1, t + 1);                                   \
        bf16x8 bh[4];                                                             \
        _Pragma("unroll") for (int n = 0; n < 4; n++)                             \
            bh[n] = *(const bf16x8*)&ldsB[buf][offB + n * 128];                   \
        _Pragma("unroll") for (int m = 0; m < 4; m++) {                           \
            bf16x8 ah = *(const bf16x8*)&ldsA[buf][0][wm][offA + m * 128];        \
            bf16x8 al = *(const bf16x8*)&ldsA[buf][1][wm][offA + m * 128];        \
            _Pragma("unroll") for (int n = 0; n < 4; n++) {                       \
                acc[m][n] = __builtin_amdgcn_mfma_f32_16x16x32_bf16(              \
                    ah, bh[n], acc[m][n], 0, 0, 0);                               \
                acc[m][n] = __builtin_amdgcn_mfma_f32_16x16x32_bf16(              \
                    al, bh[n], acc[m][n], 0, 0, 0);                               \
            }                                                                     \
        }                                                                         \
        __syncthreads();                                                          \
        buf ^= 1;                                                                 \
    }

// ---------------- WV-GEMM: A @ [W|V] -> m (bf16, cols 0..511) + p (f32, 512..1023) ----
__global__ __launch_bounds__(256, 3) void gemm_wv(
    const bf16* __restrict__ At, const bf16* __restrict__ Bt,
    bf16* __restrict__ mOut, float* __restrict__ pOut,
    int M, int KCh, int BX) {
    __shared__ bf16 ldsA[2][2][2][2048];  // [buf][plane][panel-half][64r x 32k]
    __shared__ bf16 ldsB[2][4096];        // [buf][128c x 32k] hi only
    GEMM_PROLOGUE();
    GEMM_MAINLOOP();

    int m0 = by * 128, n0 = bx * 128;
    if (n0 < 512) {  // m plane: bf16
        #pragma unroll
        for (int m = 0; m < 4; m++)
            #pragma unroll
            for (int n = 0; n < 4; n++) {
                int grow0 = m0 + wm * 64 + m * 16 + lg * 4;
                int gcol = n0 + wn * 64 + n * 16 + lr;
                #pragma unroll
                for (int r2 = 0; r2 < 4; r2++) {
                    int grow = grow0 + r2;
                    if (grow < M) mOut[(size_t)grow * 512 + gcol] = (bf16)acc[m][n][r2];
                }
            }
    } else {  // p plane: f32
        #pragma unroll
        for (int m = 0; m < 4; m++)
            #pragma unroll
            for (int n = 0; n < 4; n++) {
                int grow0 = m0 + wm * 64 + m * 16 + lg * 4;
                int gcol = n0 - 512 + wn * 64 + n * 16 + lr;
                #pragma unroll
                for (int r2 = 0; r2 < 4; r2++) {
                    int grow = grow0 + r2;
                    if (grow < M) pOut[(size_t)grow * 512 + gcol] = acc[m][n][r2];
                }
            }
    }
}

// ---------------- final GEMM: A @ Wd + bd -> f32 out ----------------
__global__ __launch_bounds__(256, 3) void gemm_out(
    const bf16* __restrict__ At, const bf16* __restrict__ Bt,
    float* __restrict__ Fout, const float* __restrict__ bias,
    int M, int N, int KCh, int BX) {
    __shared__ bf16 ldsA[2][2][2][2048];
    __shared__ bf16 ldsB[2][4096];
    GEMM_PROLOGUE();
    GEMM_MAINLOOP();

    int m0 = by * 128, n0 = bx * 128;
    #pragma unroll
    for (int m = 0; m < 4; m++)
        #pragma unroll
        for (int n = 0; n < 4; n++) {
            int grow0 = m0 + wm * 64 + m * 16 + lg * 4;
            int gcol = n0 + wn * 64 + n * 16 + lr;
            if (gcol >= N) continue;
            float bv = bias[gcol];
            #pragma unroll
            for (int r2 = 0; r2 < 4; r2++) {
                int grow = grow0 + r2;
                if (grow < M) Fout[(size_t)grow * N + gcol] = acc[m][n][r2] + bv;
            }
        }
}

// ---------------- host launch ----------------
extern "C" void kernel_launch(void* const* d_in, const int* in_sizes, int n_in,
                              void* d_out, int out_size, void* d_ws, size_t ws_size,
                              hipStream_t stream) {
    const float* x  = (const float*)d_in[0];
    const int* src  = (const int*)d_in[1];
    const int* dst  = (const int*)d_in[2];
    const float* W1 = (const float*)d_in[3];
    const float* V1 = (const float*)d_in[4];
    const float* b1 = (const float*)d_in[5];
    const float* Wk = (const float*)d_in[6];
    const float* Vk = (const float*)d_in[7];
    const float* bk = (const float*)d_in[8];
    const float* Wd = (const float*)d_in[9];
    const float* bd = (const float*)d_in[10];

    // ws layout
    int* deg_out  = (int*)d_ws;
    int* deg_in   = deg_out + 10240;
    int* offsets  = deg_in + 10240;
    int* cursor   = offsets + 10240;
    int2* edge_pk = (int2*)(cursor + 10240);            // NE packed (dst, w)
    bf16* bufA    = (bf16*)(edge_pk + NE);              // MPAN x 32 x 2048
    bf16* bufB    = bufA + (size_t)MPAN * 32 * 2048;
    bf16* w1v1t   = bufB + (size_t)MPAN * 32 * 2048;    // 8 panels x 8 x 4096 (hi only)
    bf16* wvkt    = w1v1t + (size_t)8 * 8 * 4096;       // 6 x 8 panels x 16 x 4096
    bf16* wdt     = wvkt + (size_t)6 * 8 * 16 * 4096;   // 12 panels x 16 x 4096

    // d_out doubles as m/p scratch (dead before final GEMM writes)
    float* pb = (float*)d_out;                          // [NN][512] f32
    bf16* mb  = (bf16*)(pb + (size_t)NN * 512);         // [NN][512] bf16
    float* out = (float*)d_out;

    hipMemsetAsync(deg_out, 0, 2 * 10240 * sizeof(int), stream);
    deg_kernel<<<(NE + 255) / 256, 256, 0, stream>>>(src, dst, deg_out, deg_in);
    scan_kernel<<<1, 1024, 0, stream>>>(deg_out, offsets, cursor);
    csr_kernel<<<(NE + 255) / 256, 256, 0, stream>>>(src, dst, deg_out, deg_in,
                                                     cursor, edge_pk);

    // one-time conversions (B side stores hi plane only)
    split_rows<<<(NN * (INF / 4) + 255) / 256, 256, 0, stream>>>(x, bufA, NN, INF);
    tsplit<<<dim3((512 * (INF / 8) + 255) / 256, 1, 1), 256, 0, stream>>>(
        W1, w1v1t, INF, 512, 0, 0);
    tsplit<<<dim3((512 * (INF / 8) + 255) / 256, 1, 1), 256, 0, stream>>>(
        V1, w1v1t + (size_t)4 * 8 * 4096, INF, 512, 0, 0);
    tsplit<<<dim3((512 * (CH / 8) + 255) / 256, 1, 6), 256, 0, stream>>>(
        Wk, wvkt, CH, 512, (size_t)CH * 512, (size_t)8 * 16 * 4096);
    tsplit<<<dim3((512 * (CH / 8) + 255) / 256, 1, 6), 256, 0, stream>>>(
        Vk, wvkt + (size_t)4 * 16 * 4096, CH, 512, (size_t)CH * 512,
        (size_t)8 * 16 * 4096);
    tsplit<<<dim3((NL * (CH / 8) + 255) / 256, 1, 1), 256, 0, stream>>>(
        Wd, wdt, CH, NL, 0, 0);

    dim3 blk(256);
    int gwv = (MPAN / 2) * 8;       // 632 blocks (128-row tiles x 8 col-tiles)
    int gout = (MPAN / 2) * 12;     // 948 blocks
    int gagg = 4 * ((NN + 3) / 4);  // 4 XCD-pair slices x node groups of 4

    // layer 1 (K = 256, KCh = 8)
    gemm_wv<<<gwv, blk, 0, stream>>>(bufA, w1v1t, mb, pb, NN, 8, 8);
    agg_fuse<<<gagg, blk, 0, stream>>>(mb, pb, b1, offsets, edge_pk, bufB);

    bf16* cur = bufB;
    bf16* nxt = bufA;
    for (int i = 0; i < 6; i++) {
        const bf16* WV = wvkt + (size_t)i * 8 * 16 * 4096;
        gemm_wv<<<gwv, blk, 0, stream>>>(cur, WV, mb, pb, NN, 16, 8);
        agg_fuse<<<gagg, blk, 0, stream>>>(mb, pb, bk + (size_t)i * CH, offsets,
                                           edge_pk, nxt);
        bf16* t = cur; cur = nxt; nxt = t;
    }

    // output: out = h @ Wd + bd  (K = 512, N = 1440)
    gemm_out<<<gout, blk, 0, stream>>>(cur, wdt, out, bd, NN, NL, 16, 12);
}

// Round 9
// 490.584 us; speedup vs baseline: 1.4555x; 1.0453x over previous
//
#include <hip/hip_runtime.h>
#include <hip/hip_bf16.h>
#include <stdint.h>

#define NN 10000
#define NE 160000
#define INF 256
#define CH 512
#define NL 1440
#define MPAN 158   // ceil(10000/64) A panels (64-row)

typedef __bf16 bf16;
typedef __attribute__((ext_vector_type(8))) bf16 bf16x8;
typedef __attribute__((ext_vector_type(4))) bf16 bf16x4;
typedef __attribute__((ext_vector_type(4))) float f32x4;

// A tiled layout: [panel(64 rows)][chunk(32 k')][g=4][row=64][j=8]   (2048 elem/chunk/plane)
// B tiled layout: [panel(128 cols)][chunk(32 k')][g=4][col=128][j=8] (4096 elem/chunk/plane)
// hi-plane chunks 0..KCh-1, lo-plane chunks KCh..2KCh-1. Unit order == stager lane order.
// GEMM: per-block pass count — bx >= SPLIT2 does 2-pass (ah*bh + al*bh, A ~exact);
// bx < SPLIT2 does 1-pass (ah*bh, A effectively bf16). B always bf16 (hi only).

__device__ __forceinline__ void gload16(const void* g, const void* l) {
    auto gp = reinterpret_cast<const __attribute__((address_space(1))) uint32_t*>(
        reinterpret_cast<uintptr_t>(g));
    auto lp = reinterpret_cast<__attribute__((address_space(3))) uint32_t*>(
        reinterpret_cast<uintptr_t>(l));
    __builtin_amdgcn_global_load_lds(gp, lp, 16, 0, 0);
}

// ---------------- graph prep ----------------
__global__ void deg_kernel(const int* __restrict__ src, const int* __restrict__ dst,
                           int* __restrict__ deg_out, int* __restrict__ deg_in) {
    int e = blockIdx.x * 256 + threadIdx.x;
    if (e < NE) {
        atomicAdd(&deg_out[src[e]], 1);
        atomicAdd(&deg_in[dst[e]], 1);
    }
}

__global__ __launch_bounds__(1024) void scan_kernel(const int* __restrict__ deg,
                                                    int* __restrict__ offsets,
                                                    int* __restrict__ cursor) {
    __shared__ int sums[1024];
    const int PER = 10;
    int tid = threadIdx.x;
    int base = tid * PER;
    int local[PER];
    int s = 0;
    #pragma unroll
    for (int i = 0; i < PER; i++) {
        int v = (base + i < NN) ? deg[base + i] : 0;
        local[i] = s;
        s += v;
    }
    sums[tid] = s;
    __syncthreads();
    for (int off = 1; off < 1024; off <<= 1) {
        int v = (tid >= off) ? sums[tid - off] : 0;
        __syncthreads();
        sums[tid] += v;
        __syncthreads();
    }
    int prev = (tid > 0) ? sums[tid - 1] : 0;
    #pragma unroll
    for (int i = 0; i < PER; i++) {
        if (base + i < NN) {
            int o = prev + local[i];
            offsets[base + i] = o;
            cursor[base + i] = o;
        }
    }
    if (tid == 0) offsets[NN] = sums[1023];
}

__global__ void csr_kernel(const int* __restrict__ src, const int* __restrict__ dst,
                           const int* __restrict__ deg_out, const int* __restrict__ deg_in,
                           int* __restrict__ cursor, int2* __restrict__ edge_pk) {
    int e = blockIdx.x * 256 + threadIdx.x;
    if (e < NE) {
        int s = src[e], d = dst[e];
        float dw = (float)max(deg_out[s], 1) * (float)max(deg_in[d], 1);
        float w = rsqrtf(dw);
        int pos = atomicAdd(&cursor[s], 1);
        edge_pk[pos] = make_int2(d, __float_as_int(w));
    }
}

// ------- XCD-sliced aggregate + residual + relu + split-to-tiled -------
// 4 slices x 128 channels; slice = blockIdx&3 -> pinned to XCDs {s, s+4} by
// round-robin dispatch; per-XCD mb slice = 2.56 MB (L2-resident).
// One wave per node per slice; lane handles 2 consecutive channels via u32 gather.
__global__ __launch_bounds__(256) void agg_fuse(
    const bf16* __restrict__ mb,     // [NN][512] bf16
    const float* __restrict__ pb,    // [NN][512] f32
    const float* __restrict__ bias,  // [512]
    const int* __restrict__ offsets,
    const int2* __restrict__ edge_pk,
    bf16* __restrict__ outT) {       // A-tiled split, 32 chunks (hi 0..15 | lo 16..31)
    int p = blockIdx.x;
    int slice = p & 3;
    int grp = p >> 2;
    int wid = threadIdx.x >> 6;
    int lane = threadIdx.x & 63;
    int u = grp * 4 + wid;
    if (u >= NN) return;
    int c = slice * 128 + lane * 2;          // 2 consecutive channels
    int cu = slice * 64 + lane;              // u32 index within 256-u32 row
    const uint32_t* mb32 = (const uint32_t*)mb;

    int beg = offsets[u], end = offsets[u + 1];
    float a0 = 0.f, a1 = 0.f;
    int e = beg;
    for (; e + 3 < end; e += 4) {
        int2 p0 = edge_pk[e], p1 = edge_pk[e + 1];
        int2 p2 = edge_pk[e + 2], p3 = edge_pk[e + 3];
        uint32_t q0 = mb32[p0.x * 256 + cu];
        uint32_t q1 = mb32[p1.x * 256 + cu];
        uint32_t q2 = mb32[p2.x * 256 + cu];
        uint32_t q3 = mb32[p3.x * 256 + cu];
        float w0 = __int_as_float(p0.y), w1 = __int_as_float(p1.y);
        float w2 = __int_as_float(p2.y), w3 = __int_as_float(p3.y);
        a0 += w0 * __uint_as_float(q0 << 16);
        a1 += w0 * __uint_as_float(q0 & 0xffff0000u);
        a0 += w1 * __uint_as_float(q1 << 16);
        a1 += w1 * __uint_as_float(q1 & 0xffff0000u);
        a0 += w2 * __uint_as_float(q2 << 16);
        a1 += w2 * __uint_as_float(q2 & 0xffff0000u);
        a0 += w3 * __uint_as_float(q3 << 16);
        a1 += w3 * __uint_as_float(q3 & 0xffff0000u);
    }
    for (; e < end; e++) {
        int2 pe = edge_pk[e];
        uint32_t q = mb32[pe.x * 256 + cu];
        float wt = __int_as_float(pe.y);
        a0 += wt * __uint_as_float(q << 16);
        a1 += wt * __uint_as_float(q & 0xffff0000u);
    }

    float2 pv = *(const float2*)&pb[(size_t)u * 512 + c];
    float2 bv = *(const float2*)&bias[c];
    float v0 = fmaxf(a0 + pv.x + bv.x, 0.f);
    float v1 = fmaxf(a1 + pv.y + bv.y, 0.f);
    bf16 h0 = (bf16)v0, h1 = (bf16)v1;
    bf16 l0 = (bf16)(v0 - (float)h0), l1 = (bf16)(v1 - (float)h1);

    int row = u & 63, panel = u >> 6;
    int ch = c >> 5, g = (c >> 3) & 3, j = c & 7;   // j even
    size_t base = (size_t)panel * 32 * 2048 + (size_t)ch * 2048 + g * 512 + row * 8 + j;
    uint32_t hw = (uint32_t)__builtin_bit_cast(uint16_t, h0) |
                  ((uint32_t)__builtin_bit_cast(uint16_t, h1) << 16);
    uint32_t lw = (uint32_t)__builtin_bit_cast(uint16_t, l0) |
                  ((uint32_t)__builtin_bit_cast(uint16_t, l1) << 16);
    *(uint32_t*)&outT[base] = hw;
    *(uint32_t*)&outT[base + 16 * 2048] = lw;
}

// ---------------- f32 [M][K] -> tiled split bf16 (A layout, 64-row panels) ------------
__global__ void split_rows(const float* __restrict__ in, bf16* __restrict__ out,
                           int M, int K) {
    int idx = blockIdx.x * 256 + threadIdx.x;
    int K4 = K >> 2;
    if (idx >= M * K4) return;
    int m = idx / K4;
    int k4 = (idx % K4) * 4;
    int KCh = K >> 5;
    int KC2 = KCh * 2;
    float4 v = *(const float4*)&in[(size_t)m * K + k4];
    float vv[4] = {v.x, v.y, v.z, v.w};
    bf16x4 hi, lo;
    #pragma unroll
    for (int j = 0; j < 4; j++) {
        bf16 h = (bf16)vv[j];
        hi[j] = h;
        lo[j] = (bf16)(vv[j] - (float)h);
    }
    int panel = m >> 6, row = m & 63;
    int c = k4 >> 5, g = (k4 & 31) >> 3, j0 = k4 & 7;
    size_t base = ((size_t)panel * KC2) * 2048 + g * 512 + row * 8 + j0;
    *(bf16x4*)&out[base + (size_t)c * 2048] = hi;
    *(bf16x4*)&out[base + (size_t)(KCh + c) * 2048] = lo;
}

// ---------------- W[K][N] f32 -> tiled bf16-hi (B^T layout, 128-col panels) -----------
__global__ void tsplit(const float* __restrict__ in, bf16* __restrict__ out,
                       int K, int N, size_t inStride, size_t outStride) {
    int z = blockIdx.z;
    in += (size_t)z * inStride;
    out += (size_t)z * outStride;
    int idx = blockIdx.x * 256 + threadIdx.x;
    int K8 = K >> 3;
    if (idx >= N * K8) return;
    int k8 = (idx / N) * 8;
    int n = idx % N;
    int KCh = K >> 5;
    bf16x8 hi;
    #pragma unroll
    for (int j = 0; j < 8; j++) hi[j] = (bf16)in[(size_t)(k8 + j) * N + n];
    int panel = n >> 7, row = n & 127;
    int c = k8 >> 5, g = (k8 & 31) >> 3;
    size_t base = ((size_t)panel * KCh) * 4096 + g * 1024 + row * 8;
    *(bf16x8*)&out[base + (size_t)c * 4096] = hi;
}

// -------- shared GEMM core (128x128 tile, per-block 1- or 2-pass A split) --------
#define GEMM_PROLOGUE()                                                           \
    int nwg = gridDim.x;                                                          \
    int q = nwg >> 3, r = nwg & 7;                                                \
    int p = blockIdx.x;                                                           \
    int xcd = p & 7, slot = p >> 3;                                               \
    int L = (xcd < r ? xcd * (q + 1) : r * (q + 1) + (xcd - r) * q) + slot;       \
    int by = L / BX, bx = L % BX;                                                 \
    bool use2 = (bx >= SPLIT2);                                                   \
    int tid = threadIdx.x;                                                        \
    int lane = tid & 63, w = tid >> 6;                                            \
    int wm = w >> 1, wn = w & 1;                                                  \
    int lr = lane & 15, lg = lane >> 4;                                           \
    const bf16* Ab0 = At + (size_t)(2 * by) * (KCh * 2) * 2048;                   \
    const bf16* Ab1 = At + (size_t)(2 * by + 1) * (KCh * 2) * 2048;               \
    const bf16* Bbase = Bt + (size_t)bx * KCh * 4096;                             \
    f32x4 acc[4][4];                                                              \
    _Pragma("unroll") for (int i = 0; i < 4; i++)                                 \
        _Pragma("unroll") for (int j = 0; j < 4; j++) {                           \
            f32x4 z = {0.f, 0.f, 0.f, 0.f};                                       \
            acc[i][j] = z;                                                        \
        }                                                                         \
    int u0 = tid, u1 = tid + 256;                                                 \
    int offA = lg * 512 + lr * 8;                                                 \
    int offB = lg * 1024 + (wn * 64 + lr) * 8;

#define STAGE(bufi, t)                                                            \
    do {                                                                          \
        const bf16* s0h = Ab0 + (size_t)(t) * 2048;                               \
        const bf16* s1h = Ab1 + (size_t)(t) * 2048;                               \
        const bf16* sBh = Bbase + (size_t)(t) * 4096;                             \
        gload16(s0h + tid * 8, &ldsA[bufi][0][0][tid * 8]);                       \
        gload16(s1h + tid * 8, &ldsA[bufi][0][1][tid * 8]);                       \
        gload16(sBh + u0 * 8, &ldsB[bufi][u0 * 8]);                               \
        gload16(sBh + u1 * 8, &ldsB[bufi][u1 * 8]);                               \
        if (use2) {                                                               \
            const bf16* s0l = Ab0 + (size_t)(KCh + (t)) * 2048;                   \
            const bf16* s1l = Ab1 + (size_t)(KCh + (t)) * 2048;                   \
            gload16(s0l + tid * 8, &ldsA[bufi][1][0][tid * 8]);                   \
            gload16(s1l + tid * 8, &ldsA[bufi][1][1][tid * 8]);                   \
        }                                                                         \
    } while (0)

#define GEMM_MAINLOOP()                                                           \
    STAGE(0, 0);                                                                  \
    __syncthreads();                                                              \
    int buf = 0;                                                                  \
    for (int t = 0; t < KCh; t++) {                                               \
        if (t + 1 < KCh) STAGE(buf ^ 1, t + 1);                                   \
        bf16x8 bh[4];                                                             \
        _Pragma("unroll") for (int n = 0; n < 4; n++)                             \
            bh[n] = *(const bf16x8*)&ldsB[buf][offB + n * 128];                   \
        _Pragma("unroll") for (int m = 0; m < 4; m++) {                           \
            bf16x8 ah = *(const bf16x8*)&ldsA[buf][0][wm][offA + m * 128];        \
            _Pragma("unroll") for (int n = 0; n < 4; n++)                         \
                acc[m][n] = __builtin_amdgcn_mfma_f32_16x16x32_bf16(              \
                    ah, bh[n], acc[m][n], 0, 0, 0);                               \
        }                                                                         \
        if (use2) {                                                               \
            _Pragma("unroll") for (int m = 0; m < 4; m++) {                       \
                bf16x8 al = *(const bf16x8*)&ldsA[buf][1][wm][offA + m * 128];    \
                _Pragma("unroll") for (int n = 0; n < 4; n++)                     \
                    acc[m][n] = __builtin_amdgcn_mfma_f32_16x16x32_bf16(          \
                        al, bh[n], acc[m][n], 0, 0, 0);                           \
            }                                                                     \
        }                                                                         \
        __syncthreads();                                                          \
        buf ^= 1;                                                                 \
    }

// ---------------- WV-GEMM: A @ [W|V] -> m (bf16, cols 0..511) + p (f32, 512..1023) ----
// bx < 4 (m-half): 1-pass; bx >= 4 (p-half): 2-pass.
__global__ __launch_bounds__(256, 3) void gemm_wv(
    const bf16* __restrict__ At, const bf16* __restrict__ Bt,
    bf16* __restrict__ mOut, float* __restrict__ pOut,
    int M, int KCh, int BX, int SPLIT2) {
    __shared__ bf16 ldsA[2][2][2][2048];  // [buf][plane][panel-half][64r x 32k]
    __shared__ bf16 ldsB[2][4096];        // [buf][128c x 32k] hi only
    GEMM_PROLOGUE();
    GEMM_MAINLOOP();

    int m0 = by * 128, n0 = bx * 128;
    if (n0 < 512) {  // m plane: bf16
        #pragma unroll
        for (int m = 0; m < 4; m++)
            #pragma unroll
            for (int n = 0; n < 4; n++) {
                int grow0 = m0 + wm * 64 + m * 16 + lg * 4;
                int gcol = n0 + wn * 64 + n * 16 + lr;
                #pragma unroll
                for (int r2 = 0; r2 < 4; r2++) {
                    int grow = grow0 + r2;
                    if (grow < M) mOut[(size_t)grow * 512 + gcol] = (bf16)acc[m][n][r2];
                }
            }
    } else {  // p plane: f32
        #pragma unroll
        for (int m = 0; m < 4; m++)
            #pragma unroll
            for (int n = 0; n < 4; n++) {
                int grow0 = m0 + wm * 64 + m * 16 + lg * 4;
                int gcol = n0 - 512 + wn * 64 + n * 16 + lr;
                #pragma unroll
                for (int r2 = 0; r2 < 4; r2++) {
                    int grow = grow0 + r2;
                    if (grow < M) pOut[(size_t)grow * 512 + gcol] = acc[m][n][r2];
                }
            }
    }
}

// ---------------- final GEMM: A @ Wd + bd -> f32 out (1-pass) ----------------
__global__ __launch_bounds__(256, 3) void gemm_out(
    const bf16* __restrict__ At, const bf16* __restrict__ Bt,
    float* __restrict__ Fout, const float* __restrict__ bias,
    int M, int N, int KCh, int BX, int SPLIT2) {
    __shared__ bf16 ldsA[2][2][2][2048];
    __shared__ bf16 ldsB[2][4096];
    GEMM_PROLOGUE();
    GEMM_MAINLOOP();

    int m0 = by * 128, n0 = bx * 128;
    #pragma unroll
    for (int m = 0; m < 4; m++)
        #pragma unroll
        for (int n = 0; n < 4; n++) {
            int grow0 = m0 + wm * 64 + m * 16 + lg * 4;
            int gcol = n0 + wn * 64 + n * 16 + lr;
            if (gcol >= N) continue;
            float bv = bias[gcol];
            #pragma unroll
            for (int r2 = 0; r2 < 4; r2++) {
                int grow = grow0 + r2;
                if (grow < M) Fout[(size_t)grow * N + gcol] = acc[m][n][r2] + bv;
            }
        }
}

// ---------------- host launch ----------------
extern "C" void kernel_launch(void* const* d_in, const int* in_sizes, int n_in,
                              void* d_out, int out_size, void* d_ws, size_t ws_size,
                              hipStream_t stream) {
    const float* x  = (const float*)d_in[0];
    const int* src  = (const int*)d_in[1];
    const int* dst  = (const int*)d_in[2];
    const float* W1 = (const float*)d_in[3];
    const float* V1 = (const float*)d_in[4];
    const float* b1 = (const float*)d_in[5];
    const float* Wk = (const float*)d_in[6];
    const float* Vk = (const float*)d_in[7];
    const float* bk = (const float*)d_in[8];
    const float* Wd = (const float*)d_in[9];
    const float* bd = (const float*)d_in[10];

    // ws layout
    int* deg_out  = (int*)d_ws;
    int* deg_in   = deg_out + 10240;
    int* offsets  = deg_in + 10240;
    int* cursor   = offsets + 10240;
    int2* edge_pk = (int2*)(cursor + 10240);            // NE packed (dst, w)
    bf16* bufA    = (bf16*)(edge_pk + NE);              // MPAN x 32 x 2048
    bf16* bufB    = bufA + (size_t)MPAN * 32 * 2048;
    bf16* w1v1t   = bufB + (size_t)MPAN * 32 * 2048;    // 8 panels x 8 x 4096 (hi only)
    bf16* wvkt    = w1v1t + (size_t)8 * 8 * 4096;       // 6 x 8 panels x 16 x 4096
    bf16* wdt     = wvkt + (size_t)6 * 8 * 16 * 4096;   // 12 panels x 16 x 4096

    // d_out doubles as m/p scratch (dead before final GEMM writes)
    float* pb = (float*)d_out;                          // [NN][512] f32
    bf16* mb  = (bf16*)(pb + (size_t)NN * 512);         // [NN][512] bf16
    float* out = (float*)d_out;

    hipMemsetAsync(deg_out, 0, 2 * 10240 * sizeof(int), stream);
    deg_kernel<<<(NE + 255) / 256, 256, 0, stream>>>(src, dst, deg_out, deg_in);
    scan_kernel<<<1, 1024, 0, stream>>>(deg_out, offsets, cursor);
    csr_kernel<<<(NE + 255) / 256, 256, 0, stream>>>(src, dst, deg_out, deg_in,
                                                     cursor, edge_pk);

    // one-time conversions (B side stores hi plane only)
    split_rows<<<(NN * (INF / 4) + 255) / 256, 256, 0, stream>>>(x, bufA, NN, INF);
    tsplit<<<dim3((512 * (INF / 8) + 255) / 256, 1, 1), 256, 0, stream>>>(
        W1, w1v1t, INF, 512, 0, 0);
    tsplit<<<dim3((512 * (INF / 8) + 255) / 256, 1, 1), 256, 0, stream>>>(
        V1, w1v1t + (size_t)4 * 8 * 4096, INF, 512, 0, 0);
    tsplit<<<dim3((512 * (CH / 8) + 255) / 256, 1, 6), 256, 0, stream>>>(
        Wk, wvkt, CH, 512, (size_t)CH * 512, (size_t)8 * 16 * 4096);
    tsplit<<<dim3((512 * (CH / 8) + 255) / 256, 1, 6), 256, 0, stream>>>(
        Vk, wvkt + (size_t)4 * 16 * 4096, CH, 512, (size_t)CH * 512,
        (size_t)8 * 16 * 4096);
    tsplit<<<dim3((NL * (CH / 8) + 255) / 256, 1, 1), 256, 0, stream>>>(
        Wd, wdt, CH, NL, 0, 0);

    dim3 blk(256);
    int gwv = (MPAN / 2) * 8;       // 632 blocks (128-row tiles x 8 col-tiles)
    int gout = (MPAN / 2) * 12;     // 948 blocks
    int gagg = 4 * ((NN + 3) / 4);  // 4 XCD-pair slices x node groups of 4

    // layer 1 (K = 256, KCh = 8): m-half 1-pass, p-half 2-pass
    gemm_wv<<<gwv, blk, 0, stream>>>(bufA, w1v1t, mb, pb, NN, 8, 8, 4);
    agg_fuse<<<gagg, blk, 0, stream>>>(mb, pb, b1, offsets, edge_pk, bufB);

    bf16* cur = bufB;
    bf16* nxt = bufA;
    for (int i = 0; i < 6; i++) {
        const bf16* WV = wvkt + (size_t)i * 8 * 16 * 4096;
        gemm_wv<<<gwv, blk, 0, stream>>>(cur, WV, mb, pb, NN, 16, 8, 4);
        agg_fuse<<<gagg, blk, 0, stream>>>(mb, pb, bk + (size_t)i * CH, offsets,
                                           edge_pk, nxt);
        bf16* t = cur; cur = nxt; nxt = t;
    }

    // output: out = h @ Wd + bd  (K = 512, N = 1440, all 1-pass)
    gemm_out<<<gout, blk, 0, stream>>>(cur, wdt, out, bd, NN, NL, 16, 12, 12);
}